// Round 11
// baseline (630.200 us; speedup 1.0000x reference)
//
#include <hip/hip_runtime.h>
#include <math.h>

#define BN    8
#define NN    2048
#define NP1   2049
#define VSTR  2056   // padded a/b vector stride (floats), 16B-aligned rows
#define DD    256
#define NITER 20
#define NBLK  256    // persistent grid size, 1 block/CU
#define GRP   32     // blocks per batch (independent barrier group)

typedef float f32x2 __attribute__((ext_vector_type(2)));

// ws layout: a[BN*VSTR] f32 | b[BN*VSTR] f32 | sums[41*BN] f32 | bar[BN*GRP] i32 |
//            psum[2*BN*GRP] f32 | K8[BN*NN*NN] fp8

__global__ void init_kernel(float* __restrict__ bvec, int nb, float* __restrict__ sums,
                            int* __restrict__ bar) {
    int tid = blockIdx.x * blockDim.x + threadIdx.x;
    int stride = gridDim.x * blockDim.x;
    for (int i = tid; i < nb; i += stride) bvec[i] = 1.0f;            // v0 = 0 -> b = 1
    for (int i = tid; i < 41 * BN; i += stride) sums[i] = (i < BN) ? (float)NN : 0.0f;
    if (tid < BN * GRP) bar[tid] = 0;
}

// K = exp(F^T F / 16), diag = 0. FP8 variant packs 4 cols -> u32 (OCP e4m3 HW cvt)
// into K8 (stride NN); fp32 variant writes into out's NxN (stride NP1). tj>=ti only.
template <bool FP8>
__global__ __launch_bounds__(256) void build_k_kernel(const float* __restrict__ F,
                                                      float* __restrict__ out,
                                                      unsigned char* __restrict__ K8) {
    int ti = blockIdx.x, tj = blockIdx.y, bb = blockIdx.z;
    if (tj < ti) return;
    __shared__ float As[32][64];
    __shared__ float Bs[32][64];
    int t  = threadIdx.x;
    int tx = t & 15, ty = t >> 4;
    float acc[4][4] = {};
    const float* Fb = F + (size_t)bb * DD * NN;
    int i0 = ti * 64, j0 = tj * 64;
    for (int k0 = 0; k0 < DD; k0 += 32) {
#pragma unroll
        for (int v = 0; v < 2; v++) {
            int f = t + 256 * v;
            int row = f >> 4, c4 = (f & 15) * 4;
            *(float4*)&As[row][c4] = *(const float4*)&Fb[(size_t)(k0 + row) * NN + i0 + c4];
            *(float4*)&Bs[row][c4] = *(const float4*)&Fb[(size_t)(k0 + row) * NN + j0 + c4];
        }
        __syncthreads();
#pragma unroll
        for (int k = 0; k < 32; k++) {
            float4 av = *(float4*)&As[k][ty * 4];
            float4 bv = *(float4*)&Bs[k][tx * 4];
            float ar[4] = {av.x, av.y, av.z, av.w};
            float br[4] = {bv.x, bv.y, bv.z, bv.w};
#pragma unroll
            for (int r = 0; r < 4; r++)
#pragma unroll
                for (int c = 0; c < 4; c++)
                    acc[r][c] = fmaf(ar[r], br[c], acc[r][c]);
        }
        __syncthreads();
    }
#pragma unroll
    for (int r = 0; r < 4; r++) {
        int i = i0 + ty * 4 + r;
        float kvl[4];
#pragma unroll
        for (int c = 0; c < 4; c++) {
            int j = j0 + tx * 4 + c;
            kvl[c] = (i == j) ? 0.0f : __expf(acc[r][c] * 0.0625f);  // 1/sqrt(256)
        }
        if constexpr (FP8) {
            unsigned w = __builtin_amdgcn_cvt_pk_fp8_f32(kvl[0], kvl[1], 0, false);
            w = __builtin_amdgcn_cvt_pk_fp8_f32(kvl[2], kvl[3], w, true);
            unsigned char* K8b = K8 + (size_t)bb * NN * NN;
            *(unsigned*)(K8b + (size_t)i * NN + (j0 + tx * 4)) = w;
            if (tj > ti) {
#pragma unroll
                for (int c = 0; c < 4; c++)
                    K8b[(size_t)(j0 + tx * 4 + c) * NN + i] =
                        (unsigned char)((w >> (8 * c)) & 0xff);
            }
        } else {
            float* outb = out + (size_t)bb * NP1 * NP1;
#pragma unroll
            for (int c = 0; c < 4; c++) {
                int j = j0 + tx * 4 + c;
                outb[(size_t)i * NP1 + j] = kvl[c];
                if (tj > ti) outb[(size_t)j * NP1 + i] = kvl[c];
            }
        }
    }
}

// Persistent Sinkhorn, 128 KB fp8 K-shard in LDS. R10 post-mortem: ~5-6 of
// 8.9 us/pass was TWO serialized 32-block same-address RMW chains (sums
// atomicAdd + barrier fetch_add; each cross-XCD RMW ~150-300 cy, serial).
// This round: store+parallel-poll sync — arrival is a release-STORE of the
// pass generation into the block's own slot (no round trip); wait is lanes
// 0-31 polling all 32 slots in parallel (one round trip). Bin partial sums
// likewise: per-block store into psum (parity buffered), gathered after the
// barrier by one 128-B parallel load + shfl reduce.
// 256 blocks x 1024 threads = 1 block/CU. Block b: batch=b>>5, rows
// [(b&31)*64,+64). Thread: row=tid>>4, cols [(tid&15)*128,+128).
__global__ __launch_bounds__(1024) void sink_persist(const unsigned char* __restrict__ K8,
                                                     float* __restrict__ avec,
                                                     float* __restrict__ bvec,
                                                     int* __restrict__ bar,
                                                     float* __restrict__ psum,
                                                     const float* __restrict__ alpha) {
    int blk   = blockIdx.x;
    int batch = blk >> 5;
    int rb    = blk & 31;
    int tid   = threadIdx.x;
    int seg   = tid & 15;
    int row   = tid >> 4;          // row within the 64-row shard
    int grow  = rb * 64 + row;     // global row

    __shared__ __align__(16) unsigned char Ks[64 * 2048];   // 128 KB fp8 shard
    __shared__ float xs[16 * 132];                          // padded x stage
    __shared__ float wsum[16];
    __shared__ float stot;

    // one-time stage: global (linear) -> LDS (swizzled), 128 B/thread x 8
    {
        const int4* gsrc = (const int4*)(K8 + ((size_t)batch * NN + (size_t)rb * 64) * NN);
#pragma unroll
        for (int q = 0; q < 8; q++) {
            int idx = q * 1024 + tid;
            int4 v = gsrc[idx];
            int g = idx * 16;
            int r_ = g >> 11, bir = g & 2047;
            *(int4*)&Ks[r_ * 2048 + (bir ^ (((bir >> 7) & 7) << 4))] = v;
        }
    }   // first pass's __syncthreads() covers this staging

    float* av = avec + (size_t)batch * VSTR;
    float* bv = bvec + (size_t)batch * VSTR;
    int*   gbar = bar + batch * GRP;            // this batch's arrival slots (128 B line)
    float E    = __expf(alpha[0]);
    float binA = 0.f, binB = 1.0f;
    float S_in = 2048.0f;            // sum of vector entering current pass
    int   ep   = 0;                  // pass generation
    const float4* xp4 = (const float4*)(xs + seg * 132);
    const int kbase = row * 2048;
    const int sb    = seg * 128;
    const int sx    = (seg & 7) << 4;

#define MAC16(KI, ACC)                                                          \
    {                                                                           \
        int4 kv = *(const int4*)&Ks[kbase + ((sb + (KI) * 16) ^ sx)];           \
        float4 xa = xp4[(KI) * 4 + 0], xb = xp4[(KI) * 4 + 1];                  \
        float4 xc = xp4[(KI) * 4 + 2], xd = xp4[(KI) * 4 + 3];                  \
        f32x2 p0 = __builtin_amdgcn_cvt_pk_f32_fp8(kv.x, false);                \
        f32x2 p1 = __builtin_amdgcn_cvt_pk_f32_fp8(kv.x, true);                 \
        f32x2 p2 = __builtin_amdgcn_cvt_pk_f32_fp8(kv.y, false);                \
        f32x2 p3 = __builtin_amdgcn_cvt_pk_f32_fp8(kv.y, true);                 \
        f32x2 p4 = __builtin_amdgcn_cvt_pk_f32_fp8(kv.z, false);                \
        f32x2 p5 = __builtin_amdgcn_cvt_pk_f32_fp8(kv.z, true);                 \
        f32x2 p6 = __builtin_amdgcn_cvt_pk_f32_fp8(kv.w, false);                \
        f32x2 p7 = __builtin_amdgcn_cvt_pk_f32_fp8(kv.w, true);                 \
        ACC = fmaf(p0.x, xa.x, ACC); ACC = fmaf(p0.y, xa.y, ACC);               \
        ACC = fmaf(p1.x, xa.z, ACC); ACC = fmaf(p1.y, xa.w, ACC);               \
        ACC = fmaf(p2.x, xb.x, ACC); ACC = fmaf(p2.y, xb.y, ACC);               \
        ACC = fmaf(p3.x, xb.z, ACC); ACC = fmaf(p3.y, xb.w, ACC);               \
        ACC = fmaf(p4.x, xc.x, ACC); ACC = fmaf(p4.y, xc.y, ACC);               \
        ACC = fmaf(p5.x, xc.z, ACC); ACC = fmaf(p5.y, xc.w, ACC);               \
        ACC = fmaf(p6.x, xd.x, ACC); ACC = fmaf(p6.y, xd.y, ACC);               \
        ACC = fmaf(p7.x, xd.z, ACC); ACC = fmaf(p7.y, xd.w, ACC);               \
    }

#define SINK_PASS(XIN, XOUT, BIN_IN, BIN_OUT, P, LAST)                          \
    {                                                                           \
        {   /* stage XIN[0..2048) into LDS (coalesced float2) */                \
            float2 v = ((const float2*)(XIN))[tid];                             \
            int j = tid * 2;                                                    \
            float* d = xs + ((j >> 7) * 132 + (j & 127));                       \
            d[0] = v.x; d[1] = v.y;                                             \
        }                                                                       \
        __syncthreads();                                                        \
        float dot0 = 0.f, dot1 = 0.f;                                           \
        MAC16(0, dot0) MAC16(1, dot1) MAC16(2, dot0) MAC16(3, dot1)             \
        MAC16(4, dot0) MAC16(5, dot1) MAC16(6, dot0) MAC16(7, dot1)             \
        float dot = dot0 + dot1;                                                \
        dot += __shfl_xor(dot, 1);                                              \
        dot += __shfl_xor(dot, 2);                                              \
        dot += __shfl_xor(dot, 4);                                              \
        dot += __shfl_xor(dot, 8);                                              \
        float val = (1.0f / 4096.0f) / (dot + E * (BIN_IN));                    \
        BIN_OUT = 0.5f / (E * (S_in + (BIN_IN)));                               \
        float ys = val;                                                         \
        ys += __shfl_xor(ys, 16);                                               \
        ys += __shfl_xor(ys, 32);                                               \
        if ((tid & 15) == 0) (XOUT)[grow] = val;                                \
        if ((tid & 63) == 0) wsum[tid >> 6] = ys;                               \
        __syncthreads();   /* all block stores drained (vmcnt) at barrier */    \
        if (!(LAST)) {                                                          \
            ep++;                                                               \
            float* pp = psum + (((P) & 1) * BN + batch) * GRP;                  \
            if (tid == 0) {                                                     \
                float s = 0.f;                                                  \
                _Pragma("unroll")                                               \
                for (int w = 0; w < 16; w++) s += wsum[w];                      \
                __hip_atomic_store(&pp[rb], s, __ATOMIC_RELAXED,                \
                                   __HIP_MEMORY_SCOPE_AGENT);                   \
                __builtin_amdgcn_fence(__ATOMIC_RELEASE, "agent");              \
                __hip_atomic_store(&gbar[rb], ep, __ATOMIC_RELAXED,             \
                                   __HIP_MEMORY_SCOPE_AGENT);                   \
            }                                                                   \
            if (tid < GRP) {                                                    \
                while (__hip_atomic_load(&gbar[tid], __ATOMIC_RELAXED,          \
                                         __HIP_MEMORY_SCOPE_AGENT) < ep)        \
                    __builtin_amdgcn_s_sleep(1);                                \
            }                                                                   \
            if (tid < 64) {                                                     \
                __builtin_amdgcn_fence(__ATOMIC_ACQUIRE, "agent");              \
                float ps = 0.f;                                                 \
                if (tid < GRP)                                                  \
                    ps = __hip_atomic_load(&pp[tid], __ATOMIC_RELAXED,          \
                                           __HIP_MEMORY_SCOPE_AGENT);           \
                ps += __shfl_xor(ps, 1);                                        \
                ps += __shfl_xor(ps, 2);                                        \
                ps += __shfl_xor(ps, 4);                                        \
                ps += __shfl_xor(ps, 8);                                        \
                ps += __shfl_xor(ps, 16);                                       \
                if (tid == 0) stot = ps;                                        \
            }                                                                   \
            __syncthreads();                                                    \
            S_in = stot;                                                        \
        }                                                                       \
    }

    for (int it2 = 0; it2 < NITER; it2++) {
        int p = 2 * it2 + 1;
        SINK_PASS(bv, av, binB, binA, p, false);
        SINK_PASS(av, bv, binA, binB, p + 1, (it2 == NITER - 1));
    }
#undef SINK_PASS
#undef MAC16

    if (tid == 0) { av[NN] = binA; bv[NN] = binB; }
}

// fp32 fallback pass (K in d_out, stride NP1) for ws-too-small case.
__global__ __launch_bounds__(256) void sink_pass_f32(const float* __restrict__ K,
                                                     const float* __restrict__ xin,
                                                     float* __restrict__ xout,
                                                     const float* __restrict__ sum_in,
                                                     float* __restrict__ sum_out,
                                                     const float* __restrict__ alpha) {
    int bb = blockIdx.y;
    int i0 = blockIdx.x * 16;
    __shared__ float xsl[NN];
    __shared__ float rowa[16];
    const float* xinb = xin + (size_t)bb * VSTR;
    int t = threadIdx.x;
    for (int j = t; j < NN; j += 256) xsl[j] = xinb[j];
    __syncthreads();
    float E  = __expf(alpha[0]);
    float xN = xinb[NN];
    int wave = t >> 6, lane = t & 63;
    const float* Kb = K + (size_t)bb * NP1 * NP1;
    for (int r = wave; r < 16; r += 4) {
        int i = i0 + r;
        const float* rowp = Kb + (size_t)i * NP1;
        float acc = 0.f;
        for (int j = lane; j < NN; j += 64) acc = fmaf(rowp[j], xsl[j], acc);
#pragma unroll
        for (int off = 32; off >= 1; off >>= 1) acc += __shfl_xor(acc, off);
        if (lane == 0) {
            float v = (1.0f / 4096.0f) / (acc + E * xN);
            xout[(size_t)bb * VSTR + i] = v;
            rowa[r] = v;
        }
    }
    __syncthreads();
    if (t == 0) {
        float s = 0.f;
#pragma unroll
        for (int r = 0; r < 16; r++) s += rowa[r];
        atomicAdd(sum_out + bb, s);
        if (blockIdx.x == 0) xout[(size_t)bb * VSTR + NN] = 0.5f / (E * (sum_in[bb] + xN));
    }
}

// out[i,j] = K*a_i*b_j*4096*cost (i,j<N), bins use E. FP8: K from K8; else in-place.
template <bool FP8>
__global__ __launch_bounds__(256) void final_kernel(float* __restrict__ out,
                                                    const unsigned char* __restrict__ K8,
                                                    const float* __restrict__ avec,
                                                    const float* __restrict__ bvec,
                                                    const float* __restrict__ pos,
                                                    const float* __restrict__ alpha) {
    int bb = blockIdx.y;
    int i0 = blockIdx.x * 16;
    __shared__ float as_[16], ys[16], xs2[16];
    int t = threadIdx.x;
    if (t < 16) {
        int i = i0 + t;
        as_[t] = (i < NP1) ? avec[(size_t)bb * VSTR + i] : 0.f;
        if (i < NN) {
            ys[t]  = pos[((size_t)bb * NN + i) * 2 + 0];
            xs2[t] = pos[((size_t)bb * NN + i) * 2 + 1];
        } else {
            ys[t] = 1e9f; xs2[t] = 1e9f;
        }
    }
    __syncthreads();
    float E = __expf(alpha[0]);
    float* outb = out + (size_t)bb * NP1 * NP1;
    const unsigned char* K8b = K8 + (size_t)bb * NN * NN;
    for (int j = t; j < NP1; j += 256) {
        float bj = bvec[(size_t)bb * VSTR + j];
        bool jin = (j < NN);
        float yj = 0.f, xj = 0.f;
        if (jin) {
            yj = pos[((size_t)bb * NN + j) * 2 + 0];
            xj = pos[((size_t)bb * NN + j) * 2 + 1];
        }
#pragma unroll 1
        for (int r = 0; r < 16; r++) {
            int i = i0 + r;
            if (i >= NP1) break;
            size_t idx = (size_t)i * NP1 + j;
            float v;
            if (i < NN && jin) {
                float Kv;
                if constexpr (FP8)
                    Kv = __builtin_amdgcn_cvt_f32_fp8((int)K8b[(size_t)i * NN + j], 0);
                else
                    Kv = outb[idx];
                bool c = (fabsf(ys[r] - yj) <= 0.1f) && (fabsf(xs2[r] - xj) <= 0.1f);
                v = c ? Kv * as_[r] * bj * 4096.0f : 0.0f;
            } else {
                v = E * as_[r] * bj * 4096.0f;
            }
            outb[idx] = v;
        }
    }
}

extern "C" void kernel_launch(void* const* d_in, const int* in_sizes, int n_in,
                              void* d_out, int out_size, void* d_ws, size_t ws_size,
                              hipStream_t stream) {
    const float* F     = (const float*)d_in[0];  // (B, D, N)
    const float* pos   = (const float*)d_in[1];  // (B, N, 2)
    const float* alpha = (const float*)d_in[3];  // (1,)
    float* out = (float*)d_out;
    float* ws  = (float*)d_ws;

    float* avec = ws;
    float* bvec = ws + BN * VSTR;
    float* sums = ws + 2 * BN * VSTR;                 // 41*BN floats (fallback path)
    int*   bar  = (int*)(sums + 41 * BN);             // BN x GRP arrival slots
    float* psum = (float*)(bar + BN * GRP);           // 2 x BN x GRP partial sums
    unsigned char* K8 = (unsigned char*)(psum + 2 * BN * GRP);  // 33.5 MB fp8

    size_t need = (size_t)(2 * BN * VSTR + 41 * BN + 3 * BN * GRP) * 4
                + (size_t)BN * NN * NN;
    bool fp8 = (ws_size >= need);

    hipLaunchKernelGGL(init_kernel, dim3(64), dim3(256), 0, stream, bvec, BN * VSTR,
                       sums, bar);

    if (fp8) {
        hipLaunchKernelGGL((build_k_kernel<true>), dim3(32, 32, BN), dim3(256), 0, stream,
                           F, out, K8);
        const unsigned char* Kp = K8;
        float* ap = avec; float* bp = bvec; int* brp = bar; float* pp = psum;
        const float* alp = alpha;
        void* params[6] = {(void*)&Kp, (void*)&ap, (void*)&bp, (void*)&brp,
                           (void*)&pp, (void*)&alp};
        hipLaunchCooperativeKernel((const void*)sink_persist, dim3(NBLK), dim3(1024),
                                   params, 0, stream);
        hipLaunchKernelGGL((final_kernel<true>), dim3((NP1 + 15) / 16, BN), dim3(256), 0,
                           stream, out, K8, avec, bvec, pos, alpha);
    } else {
        hipLaunchKernelGGL((build_k_kernel<false>), dim3(32, 32, BN), dim3(256), 0, stream,
                           F, out, K8);
        const float* xin = bvec;
        float* xout = avec;
        for (int p = 1; p <= 2 * NITER; p++) {
            hipLaunchKernelGGL(sink_pass_f32, dim3(NN / 16, BN), dim3(256), 0, stream,
                               out, xin, xout, sums + (p - 1) * BN, sums + p * BN, alpha);
            float* tmp = (float*)xin; xin = xout; xout = tmp;
        }
        hipLaunchKernelGGL((final_kernel<false>), dim3((NP1 + 15) / 16, BN), dim3(256), 0,
                           stream, out, K8, avec, bvec, pos, alpha);
    }
}